// Round 21
// baseline (371.458 us; speedup 1.0000x reference)
//
#include <hip/hip_runtime.h>
#include <vector>
#include <algorithm>
#include <utility>

typedef unsigned long long u64;
typedef unsigned int u32;

#define NTRIP 110592              // 48^3 distinct (c0,c1,c2)
#define NKEYS (NTRIP * 64)        // 7,077,888 possible keys (key <-> voxel bijection)
#define NW NTRIP                  // bitmap words
#define NBKT (NW / 256)           // 432 buckets of 256 words
#define MPAD 16                   // padded member slots per multi voxel (= one 64B line)
#define MCAP 524288               // max multi voxels supported (actual ~235K)

struct Combo {                    // 32B: what k_points needs per word
    u64 bm;                       // occupancy bits
    u64 mm;                       // multi bits
    u32 g;                        // gid base for this word
    u32 mg;                       // mgid base
    u32 iv;                       // (unused by k_points; kept for alignment)
    u32 pad;
};

// ======== host-side: rank table for the 110,592 triple-hashes ========
// full hash = fnv3p(c0,c1,c2) ^ c3 (c3 < 64 flips only low 6 bits).
// rank48[tau] = (rank_of_hash << 6) | (hash & 63); point key = rank48[tau]^c3 (23 bits)
static u32 g_rank48[NTRIP];
namespace {
struct RankInit {
    RankInit() {
        std::vector<std::pair<u64, u32>> v(NTRIP);
        for (u32 t = 0; t < NTRIP; t++) {
            u64 h = 14695981039346656037ull;
            const u64 P = 1099511628211ull;
            h *= P; h ^= (u64)(t / 2304);
            h *= P; h ^= (u64)((t % 2304) / 48);
            h *= P; h ^= (u64)(t % 48);
            h *= P;
            v[t] = {h, t};
        }
        std::sort(v.begin(), v.end());
        for (u32 p = 0; p < NTRIP; p++)
            g_rank48[v[p].second] = (p << 6) | (u32)(v[p].first & 63ull);
    }
};
static RankInit g_rank_init;
}

// ======== K1: key + ONE fire-and-forget atomic; keyrec[kk] = (idxsum<<8)|count ====
__global__ void k_key(const int* __restrict__ coords, const u32* __restrict__ rank48,
                      u32* __restrict__ pkey, u32* __restrict__ keyrec, int N) {
    int i = blockIdx.x * blockDim.x + threadIdx.x;
    if (i >= N) return;
    int4 c = ((const int4*)coords)[i];
    u32 tau = (u32)c.x * 2304u + (u32)c.y * 48u + (u32)c.z;
    u32 kk = rank48[tau] ^ (u32)c.w;
    atomicAdd(&keyrec[kk], ((u32)i << 8) | 1u);   // non-returning form
    pkey[i] = kk;
}

// ======== K2: popcount prefixes (bm/mm in registers) + invrank ========
__global__ void k_prefix(const u32* __restrict__ keyrec, const u32* __restrict__ rank48,
                         u32* __restrict__ wprefix, u32* __restrict__ mprefix,
                         u32* __restrict__ dtotal, u32* __restrict__ mtotal,
                         u32* __restrict__ invrank) {
    __shared__ u32 s[256];
    int t = threadIdx.x, b = blockIdx.x;
    int w = b * 256 + t;
    u32 r = rank48[w];
    invrank[r >> 6] = ((u32)w << 6) | (r & 63u);
    u64 bm = 0, mm = 0;
    const uint4* kr = (const uint4*)(keyrec + (size_t)w * 64);
#pragma unroll
    for (int q = 0; q < 16; q++) {
        uint4 v = kr[q];
        int bit = q * 4;
        u32 c0 = v.x & 0xFFu, c1 = v.y & 0xFFu, c2 = v.z & 0xFFu, c3v = v.w & 0xFFu;
        bm |= ((u64)(c0 ? 1u : 0u) << bit) | ((u64)(c1 ? 1u : 0u) << (bit + 1)) |
              ((u64)(c2 ? 1u : 0u) << (bit + 2)) | ((u64)(c3v ? 1u : 0u) << (bit + 3));
        mm |= ((u64)(c0 >= 2u ? 1u : 0u) << bit) | ((u64)(c1 >= 2u ? 1u : 0u) << (bit + 1)) |
              ((u64)(c2 >= 2u ? 1u : 0u) << (bit + 2)) | ((u64)(c3v >= 2u ? 1u : 0u) << (bit + 3));
    }
    u32 c = (u32)__popcll(bm);
    s[t] = c;
    __syncthreads();
    for (int off = 1; off < 256; off <<= 1) {
        u32 v = (t >= off) ? s[t - off] : 0u;
        __syncthreads();
        s[t] += v;
        __syncthreads();
    }
    wprefix[w] = s[t] - c;
    if (t == 255) dtotal[b] = s[255];
    __syncthreads();
    u32 m = (u32)__popcll(mm);
    s[t] = m;
    __syncthreads();
    for (int off = 1; off < 256; off <<= 1) {
        u32 v = (t >= off) ? s[t - off] : 0u;
        __syncthreads();
        s[t] += v;
        __syncthreads();
    }
    mprefix[w] = s[t] - m;
    if (t == 255) mtotal[b] = s[255];
}

// ======== K3: exclusive scans over the 432 buckets ========
__global__ void k_meta(const u32* __restrict__ dtotal, const u32* __restrict__ mtotal,
                       u32* __restrict__ gidbase, u32* __restrict__ mgidbase,
                       u32* __restrict__ nvslot) {
    __shared__ u32 s[256];
    int t = threadIdx.x;
    u32 a = (2 * t < NBKT) ? dtotal[2 * t] : 0u;
    u32 b = (2 * t + 1 < NBKT) ? dtotal[2 * t + 1] : 0u;
    u32 sum = a + b;
    s[t] = sum;
    __syncthreads();
    for (int off = 1; off < 256; off <<= 1) {
        u32 v = (t >= off) ? s[t - off] : 0u;
        __syncthreads();
        s[t] += v;
        __syncthreads();
    }
    u32 tb = s[t] - sum;
    if (2 * t < NBKT) gidbase[2 * t] = tb;
    if (2 * t + 1 < NBKT) gidbase[2 * t + 1] = tb + a;
    if (t == 255) nvslot[0] = s[255];
    __syncthreads();
    u32 a2 = (2 * t < NBKT) ? mtotal[2 * t] : 0u;
    u32 b2 = (2 * t + 1 < NBKT) ? mtotal[2 * t + 1] : 0u;
    u32 sum2 = a2 + b2;
    s[t] = sum2;
    __syncthreads();
    for (int off = 1; off < 256; off <<= 1) {
        u32 v = (t >= off) ? s[t - off] : 0u;
        __syncthreads();
        s[t] += v;
        __syncthreads();
    }
    u32 tb2 = s[t] - sum2;
    if (2 * t < NBKT) mgidbase[2 * t] = tb2;
    if (2 * t + 1 < NBKT) mgidbase[2 * t + 1] = tb2 + a2;
}

// ======== K3b: emit combo (for k_points) + voxinfo (for k_vox) ========
// voxinfo[gid] = pay(24) | c(8)<<24 | j(6)<<32 | iv(23)<<38
__global__ void k_emit(const u32* __restrict__ keyrec, const u32* __restrict__ wprefix,
                       const u32* __restrict__ mprefix, const u32* __restrict__ gidbase,
                       const u32* __restrict__ mgidbase, const u32* __restrict__ invrank,
                       Combo* __restrict__ combo, u64* __restrict__ voxinfo) {
    int w = blockIdx.x * 256 + threadIdx.x;
    u32 g = gidbase[w >> 8] + wprefix[w];
    u32 mg = mgidbase[w >> 8] + mprefix[w];
    u32 iv = invrank[w];
    u64 bm = 0, mm = 0;
    u32 gg = g, mgg = mg;
    const u32* kr = keyrec + (size_t)w * 64;
#pragma unroll 4
    for (int j = 0; j < 64; j++) {
        u32 rec = kr[j];
        u32 c = rec & 0xFFu;
        if (c) {
            bm |= 1ull << j;
            u32 pay;
            if (c >= 2u) {
                mm |= 1ull << j;
                pay = mgg++;
            } else {
                pay = (rec >> 8) & 0xFFFFFFu;
            }
            u32 cc = c > MPAD ? (u32)MPAD : c;
            voxinfo[gg++] = (u64)pay | ((u64)cc << 24) | ((u64)(u32)j << 32) |
                            ((u64)iv << 38);
        }
    }
    Combo cb;
    cb.bm = bm; cb.mm = mm; cb.g = g; cb.mg = mg; cb.iv = iv; cb.pad = 0;
    combo[w] = cb;
}

// ======== K4: per point -- v2p + midx (multis only) ========
__global__ void k_points(const u32* __restrict__ pkey, const Combo* __restrict__ combo,
                         u32* __restrict__ mcnt, u32* __restrict__ midx,
                         float* __restrict__ v2p, int N) {
    int i = blockIdx.x * blockDim.x + threadIdx.x;
    if (i >= N) return;
    u32 kk = pkey[i];
    Combo cb = combo[kk >> 6];                 // ONE 32B gather
    u64 lowmask = (1ull << (kk & 63u)) - 1ull;
    u32 gid = cb.g + (u32)__popcll(cb.bm & lowmask);
    v2p[i] = (float)gid;                       // coalesced
    if ((cb.mm >> (kk & 63u)) & 1ull) {
        u32 mgid = cb.mg + (u32)__popcll(cb.mm & lowmask);
        u32 slot = atomicAdd(&mcnt[mgid], 1u);
        if (slot < MPAD) midx[(size_t)mgid * MPAD + slot] = (u32)i;
    }
    // singletons: index already in voxinfo payload (keyrec idxsum)
}

// ======== K5: thread-per-output-row; coalesced meta, gathered feats ========
__global__ void k_vox(const u64* __restrict__ voxinfo, const u32* __restrict__ midx,
                      const float* __restrict__ feats, const u32* __restrict__ nvslot,
                      float* __restrict__ vox_feats, float* __restrict__ vox_coords,
                      float* __restrict__ nvox, int N) {
    int t = blockIdx.x * blockDim.x + threadIdx.x;
    if (t >= N) return;
    u32 nv = nvslot[0];
    if (t == 0) nvox[0] = (float)nv;
    if ((u32)t >= nv) {   // padding rows
        float4 z = {0, 0, 0, 0};
        float4* vf = (float4*)(vox_feats + (size_t)t * 16);
        vf[0] = z; vf[1] = z; vf[2] = z; vf[3] = z;
        *(float4*)(vox_coords + (size_t)t * 4) = z;
        return;
    }
    u64 vi = voxinfo[t];                            // coalesced 8B
    u32 pay = (u32)vi & 0xFFFFFFu;
    u32 c = (u32)(vi >> 24) & 0xFFu;
    u32 j = (u32)(vi >> 32) & 63u;
    u32 iv = (u32)(vi >> 38);
    u32 tau = iv >> 6;
    u32 c3 = (j ^ iv) & 63u;
    *(float4*)(vox_coords + (size_t)t * 4) =
        make_float4((float)(tau / 2304u), (float)((tau % 2304u) / 48u),
                    (float)(tau % 48u), (float)c3);
    u32 ii[MPAD];
    ii[0] = pay;                    // singleton: pay == point index
#pragma unroll
    for (int q = 1; q < MPAD; q++) ii[q] = 0u;
    if (c > 1) {
        const uint4* ml = (const uint4*)(midx + (size_t)pay * MPAD);
        uint4 L0 = ml[0], L1 = ml[1], L2 = ml[2], L3 = ml[3];
        ii[0] = L0.x; ii[1] = L0.y; ii[2] = L0.z; ii[3] = L0.w;
        ii[4] = L1.x; ii[5] = L1.y; ii[6] = L1.z; ii[7] = L1.w;
        ii[8] = L2.x; ii[9] = L2.y; ii[10] = L2.z; ii[11] = L2.w;
        ii[12] = L3.x; ii[13] = L3.y; ii[14] = L3.z; ii[15] = L3.w;
    }
    float4 a0 = {0, 0, 0, 0}, a1 = {0, 0, 0, 0}, a2 = {0, 0, 0, 0}, a3 = {0, 0, 0, 0};
#pragma unroll
    for (int q = 0; q < MPAD; q++) {
        if (q < (int)c) {
            const float4* f = (const float4*)(feats + (size_t)ii[q] * 16);
            float4 v0 = f[0], v1 = f[1], v2 = f[2], v3 = f[3];
            a0.x += v0.x; a0.y += v0.y; a0.z += v0.z; a0.w += v0.w;
            a1.x += v1.x; a1.y += v1.y; a1.z += v1.z; a1.w += v1.w;
            a2.x += v2.x; a2.y += v2.y; a2.z += v2.z; a2.w += v2.w;
            a3.x += v3.x; a3.y += v3.y; a3.z += v3.z; a3.w += v3.w;
        }
    }
    float inv = 1.0f / (float)c;
    float4* vf = (float4*)(vox_feats + (size_t)t * 16);
    vf[0] = make_float4(a0.x * inv, a0.y * inv, a0.z * inv, a0.w * inv);
    vf[1] = make_float4(a1.x * inv, a1.y * inv, a1.z * inv, a1.w * inv);
    vf[2] = make_float4(a2.x * inv, a2.y * inv, a2.z * inv, a2.w * inv);
    vf[3] = make_float4(a3.x * inv, a3.y * inv, a3.z * inv, a3.w * inv);
}

extern "C" void kernel_launch(void* const* d_in, const int* in_sizes, int n_in,
                              void* d_out, int out_size, void* d_ws, size_t ws_size,
                              hipStream_t stream) {
    const int* coords = (const int*)d_in[0];
    const float* feats = (const float*)d_in[1];
    int N = in_sizes[0] / 4;

    float* out = (float*)d_out;
    float* vox_feats = out;                      // N*16
    float* vox_coords = out + (size_t)N * 16;    // N*4
    float* v2p = vox_coords + (size_t)N * 4;     // N
    float* nvox = v2p + (size_t)N;               // 1

    // NOTE: keyrec and mcnt are contiguous -> zeroed with ONE memset.
    char* w = (char*)d_ws;
    u32* keyrec = (u32*)w;     w += (size_t)NKEYS * 4;         // 28.3 MB (memset)
    u32* mcnt = (u32*)w;       w += (size_t)MCAP * 4;          // 2 MB (memset)
    u32* pkey = (u32*)w;       w += (size_t)N * 4;             // 8 MB
    u32* midx = (u32*)w;       w += (size_t)MCAP * MPAD * 4;   // 33.5 MB
    u64* voxinfo = (u64*)w;    w += (size_t)N * 8;             // 16 MB
    Combo* combo = (Combo*)w;  w += (size_t)NW * sizeof(Combo);// 3.5 MB
    u32* wprefix = (u32*)w;    w += (size_t)NW * 4;
    u32* mprefix = (u32*)w;    w += (size_t)NW * 4;
    u32* dtotal = (u32*)w;     w += 512 * 4;
    u32* mtotal = (u32*)w;     w += 512 * 4;
    u32* gidbase = (u32*)w;    w += 512 * 4;
    u32* mgidbase = (u32*)w;   w += 512 * 4;
    u32* rank48_d = (u32*)w;   w += (size_t)NTRIP * 4;
    u32* invrank_d = (u32*)w;  w += (size_t)NTRIP * 4;
    u32* nvslot = (u32*)w;     w += 256;

    hipMemcpyAsync(rank48_d, g_rank48, sizeof(g_rank48), hipMemcpyHostToDevice, stream);
    hipMemsetAsync(keyrec, 0, (size_t)NKEYS * 4 + (size_t)MCAP * 4, stream);

    int blocksN = (N + 255) / 256;

    k_key<<<blocksN, 256, 0, stream>>>(coords, rank48_d, pkey, keyrec, N);
    k_prefix<<<NBKT, 256, 0, stream>>>(keyrec, rank48_d, wprefix, mprefix,
                                       dtotal, mtotal, invrank_d);
    k_meta<<<1, 256, 0, stream>>>(dtotal, mtotal, gidbase, mgidbase, nvslot);
    k_emit<<<NBKT, 256, 0, stream>>>(keyrec, wprefix, mprefix, gidbase, mgidbase,
                                     invrank_d, combo, voxinfo);
    k_points<<<blocksN, 256, 0, stream>>>(pkey, combo, mcnt, midx, v2p, N);
    k_vox<<<blocksN, 256, 0, stream>>>(voxinfo, midx, feats, nvslot,
                                       vox_feats, vox_coords, nvox, N);
}

// Round 22
// 371.083 us; speedup vs baseline: 1.0010x; 1.0010x over previous
//
#include <hip/hip_runtime.h>
#include <vector>
#include <algorithm>
#include <utility>

typedef unsigned long long u64;
typedef unsigned int u32;

#define NTRIP 110592              // 48^3 distinct (c0,c1,c2)
#define NKEYS (NTRIP * 64)        // 7,077,888 possible keys (key <-> voxel bijection)
#define NW NTRIP                  // bitmap words
#define NBKT (NW / 256)           // 432 buckets of 256 words
#define MPAD 16                   // padded member slots per multi voxel (= one 64B line)
#define MCAP 524288               // max multi voxels supported (actual ~235K)

struct Combo {                    // 32B: what k_points needs per word
    u64 bm;                       // occupancy bits
    u64 mm;                       // multi bits
    u32 g;                        // gid base for this word
    u32 mg;                       // mgid base
    u32 iv;                       // (unused by k_points; kept for alignment)
    u32 pad;
};

// ======== host-side: rank table for the 110,592 triple-hashes ========
// full hash = fnv3p(c0,c1,c2) ^ c3 (c3 < 64 flips only low 6 bits).
// rank48[tau] = (rank_of_hash << 6) | (hash & 63); point key = rank48[tau]^c3 (23 bits)
static u32 g_rank48[NTRIP];
namespace {
struct RankInit {
    RankInit() {
        std::vector<std::pair<u64, u32>> v(NTRIP);
        for (u32 t = 0; t < NTRIP; t++) {
            u64 h = 14695981039346656037ull;
            const u64 P = 1099511628211ull;
            h *= P; h ^= (u64)(t / 2304);
            h *= P; h ^= (u64)((t % 2304) / 48);
            h *= P; h ^= (u64)(t % 48);
            h *= P;
            v[t] = {h, t};
        }
        std::sort(v.begin(), v.end());
        for (u32 p = 0; p < NTRIP; p++)
            g_rank48[v[p].second] = (p << 6) | (u32)(v[p].first & 63ull);
    }
};
static RankInit g_rank_init;
}

// ======== K1: key + ONE fire-and-forget atomic; keyrec[kk] = (idxsum<<8)|count ====
__global__ void k_key(const int* __restrict__ coords, const u32* __restrict__ rank48,
                      u32* __restrict__ pkey, u32* __restrict__ keyrec, int N) {
    int i = blockIdx.x * blockDim.x + threadIdx.x;
    if (i >= N) return;
    int4 c = ((const int4*)coords)[i];
    u32 tau = (u32)c.x * 2304u + (u32)c.y * 48u + (u32)c.z;
    u32 kk = rank48[tau] ^ (u32)c.w;
    atomicAdd(&keyrec[kk], ((u32)i << 8) | 1u);   // non-returning form
    pkey[i] = kk;
}

// ======== K2: popcount prefixes (bm/mm in registers) + invrank ========
__global__ void k_prefix(const u32* __restrict__ keyrec, const u32* __restrict__ rank48,
                         u32* __restrict__ wprefix, u32* __restrict__ mprefix,
                         u32* __restrict__ dtotal, u32* __restrict__ mtotal,
                         u32* __restrict__ invrank) {
    __shared__ u32 s[256];
    int t = threadIdx.x, b = blockIdx.x;
    int w = b * 256 + t;
    u32 r = rank48[w];
    invrank[r >> 6] = ((u32)w << 6) | (r & 63u);
    u64 bm = 0, mm = 0;
    const uint4* kr = (const uint4*)(keyrec + (size_t)w * 64);
#pragma unroll
    for (int q = 0; q < 16; q++) {
        uint4 v = kr[q];
        int bit = q * 4;
        u32 c0 = v.x & 0xFFu, c1 = v.y & 0xFFu, c2 = v.z & 0xFFu, c3v = v.w & 0xFFu;
        bm |= ((u64)(c0 ? 1u : 0u) << bit) | ((u64)(c1 ? 1u : 0u) << (bit + 1)) |
              ((u64)(c2 ? 1u : 0u) << (bit + 2)) | ((u64)(c3v ? 1u : 0u) << (bit + 3));
        mm |= ((u64)(c0 >= 2u ? 1u : 0u) << bit) | ((u64)(c1 >= 2u ? 1u : 0u) << (bit + 1)) |
              ((u64)(c2 >= 2u ? 1u : 0u) << (bit + 2)) | ((u64)(c3v >= 2u ? 1u : 0u) << (bit + 3));
    }
    u32 c = (u32)__popcll(bm);
    s[t] = c;
    __syncthreads();
    for (int off = 1; off < 256; off <<= 1) {
        u32 v = (t >= off) ? s[t - off] : 0u;
        __syncthreads();
        s[t] += v;
        __syncthreads();
    }
    wprefix[w] = s[t] - c;
    if (t == 255) dtotal[b] = s[255];
    __syncthreads();
    u32 m = (u32)__popcll(mm);
    s[t] = m;
    __syncthreads();
    for (int off = 1; off < 256; off <<= 1) {
        u32 v = (t >= off) ? s[t - off] : 0u;
        __syncthreads();
        s[t] += v;
        __syncthreads();
    }
    mprefix[w] = s[t] - m;
    if (t == 255) mtotal[b] = s[255];
}

// ======== K3: exclusive scans over the 432 buckets ========
__global__ void k_meta(const u32* __restrict__ dtotal, const u32* __restrict__ mtotal,
                       u32* __restrict__ gidbase, u32* __restrict__ mgidbase,
                       u32* __restrict__ nvslot) {
    __shared__ u32 s[256];
    int t = threadIdx.x;
    u32 a = (2 * t < NBKT) ? dtotal[2 * t] : 0u;
    u32 b = (2 * t + 1 < NBKT) ? dtotal[2 * t + 1] : 0u;
    u32 sum = a + b;
    s[t] = sum;
    __syncthreads();
    for (int off = 1; off < 256; off <<= 1) {
        u32 v = (t >= off) ? s[t - off] : 0u;
        __syncthreads();
        s[t] += v;
        __syncthreads();
    }
    u32 tb = s[t] - sum;
    if (2 * t < NBKT) gidbase[2 * t] = tb;
    if (2 * t + 1 < NBKT) gidbase[2 * t + 1] = tb + a;
    if (t == 255) nvslot[0] = s[255];
    __syncthreads();
    u32 a2 = (2 * t < NBKT) ? mtotal[2 * t] : 0u;
    u32 b2 = (2 * t + 1 < NBKT) ? mtotal[2 * t + 1] : 0u;
    u32 sum2 = a2 + b2;
    s[t] = sum2;
    __syncthreads();
    for (int off = 1; off < 256; off <<= 1) {
        u32 v = (t >= off) ? s[t - off] : 0u;
        __syncthreads();
        s[t] += v;
        __syncthreads();
    }
    u32 tb2 = s[t] - sum2;
    if (2 * t < NBKT) mgidbase[2 * t] = tb2;
    if (2 * t + 1 < NBKT) mgidbase[2 * t + 1] = tb2 + a2;
}

// ======== K3b: emit combo (for k_points) + voxinfo (for k_vox) ========
// voxinfo[gid] = pay(24) | c(8)<<24 | j(6)<<32 | iv(23)<<38
__global__ void k_emit(const u32* __restrict__ keyrec, const u32* __restrict__ wprefix,
                       const u32* __restrict__ mprefix, const u32* __restrict__ gidbase,
                       const u32* __restrict__ mgidbase, const u32* __restrict__ invrank,
                       Combo* __restrict__ combo, u64* __restrict__ voxinfo) {
    int w = blockIdx.x * 256 + threadIdx.x;
    u32 g = gidbase[w >> 8] + wprefix[w];
    u32 mg = mgidbase[w >> 8] + mprefix[w];
    u32 iv = invrank[w];
    u64 bm = 0, mm = 0;
    u32 gg = g, mgg = mg;
    const u32* kr = keyrec + (size_t)w * 64;
#pragma unroll 4
    for (int j = 0; j < 64; j++) {
        u32 rec = kr[j];
        u32 c = rec & 0xFFu;
        if (c) {
            bm |= 1ull << j;
            u32 pay;
            if (c >= 2u) {
                mm |= 1ull << j;
                pay = mgg++;
            } else {
                pay = (rec >> 8) & 0xFFFFFFu;
            }
            u32 cc = c > MPAD ? (u32)MPAD : c;
            voxinfo[gg++] = (u64)pay | ((u64)cc << 24) | ((u64)(u32)j << 32) |
                            ((u64)iv << 38);
        }
    }
    Combo cb;
    cb.bm = bm; cb.mm = mm; cb.g = g; cb.mg = mg; cb.iv = iv; cb.pad = 0;
    combo[w] = cb;
}

// ======== K4: per point -- v2p + midx (multis only) ========
__global__ void k_points(const u32* __restrict__ pkey, const Combo* __restrict__ combo,
                         u32* __restrict__ mcnt, u32* __restrict__ midx,
                         float* __restrict__ v2p, int N) {
    int i = blockIdx.x * blockDim.x + threadIdx.x;
    if (i >= N) return;
    u32 kk = pkey[i];
    Combo cb = combo[kk >> 6];                 // ONE 32B gather
    u64 lowmask = (1ull << (kk & 63u)) - 1ull;
    u32 gid = cb.g + (u32)__popcll(cb.bm & lowmask);
    v2p[i] = (float)gid;                       // coalesced
    if ((cb.mm >> (kk & 63u)) & 1ull) {
        u32 mgid = cb.mg + (u32)__popcll(cb.mm & lowmask);
        u32 slot = atomicAdd(&mcnt[mgid], 1u);
        if (slot < MPAD) midx[(size_t)mgid * MPAD + slot] = (u32)i;
    }
    // singletons: index already in voxinfo payload (keyrec idxsum)
}

// ======== K5: thread-per-output-row; coalesced meta, gathered feats ========
__global__ void k_vox(const u64* __restrict__ voxinfo, const u32* __restrict__ midx,
                      const float* __restrict__ feats, const u32* __restrict__ nvslot,
                      float* __restrict__ vox_feats, float* __restrict__ vox_coords,
                      float* __restrict__ nvox, int N) {
    int t = blockIdx.x * blockDim.x + threadIdx.x;
    if (t >= N) return;
    u32 nv = nvslot[0];
    if (t == 0) nvox[0] = (float)nv;
    if ((u32)t >= nv) {   // padding rows
        float4 z = {0, 0, 0, 0};
        float4* vf = (float4*)(vox_feats + (size_t)t * 16);
        vf[0] = z; vf[1] = z; vf[2] = z; vf[3] = z;
        *(float4*)(vox_coords + (size_t)t * 4) = z;
        return;
    }
    u64 vi = voxinfo[t];                            // coalesced 8B
    u32 pay = (u32)vi & 0xFFFFFFu;
    u32 c = (u32)(vi >> 24) & 0xFFu;
    u32 j = (u32)(vi >> 32) & 63u;
    u32 iv = (u32)(vi >> 38);
    u32 tau = iv >> 6;
    u32 c3 = (j ^ iv) & 63u;
    *(float4*)(vox_coords + (size_t)t * 4) =
        make_float4((float)(tau / 2304u), (float)((tau % 2304u) / 48u),
                    (float)(tau % 48u), (float)c3);
    u32 ii[MPAD];
    ii[0] = pay;                    // singleton: pay == point index
#pragma unroll
    for (int q = 1; q < MPAD; q++) ii[q] = 0u;
    if (c > 1) {
        const uint4* ml = (const uint4*)(midx + (size_t)pay * MPAD);
        uint4 L0 = ml[0], L1 = ml[1], L2 = ml[2], L3 = ml[3];
        ii[0] = L0.x; ii[1] = L0.y; ii[2] = L0.z; ii[3] = L0.w;
        ii[4] = L1.x; ii[5] = L1.y; ii[6] = L1.z; ii[7] = L1.w;
        ii[8] = L2.x; ii[9] = L2.y; ii[10] = L2.z; ii[11] = L2.w;
        ii[12] = L3.x; ii[13] = L3.y; ii[14] = L3.z; ii[15] = L3.w;
    }
    float4 a0 = {0, 0, 0, 0}, a1 = {0, 0, 0, 0}, a2 = {0, 0, 0, 0}, a3 = {0, 0, 0, 0};
#pragma unroll
    for (int q = 0; q < MPAD; q++) {
        if (q < (int)c) {
            const float4* f = (const float4*)(feats + (size_t)ii[q] * 16);
            float4 v0 = f[0], v1 = f[1], v2 = f[2], v3 = f[3];
            a0.x += v0.x; a0.y += v0.y; a0.z += v0.z; a0.w += v0.w;
            a1.x += v1.x; a1.y += v1.y; a1.z += v1.z; a1.w += v1.w;
            a2.x += v2.x; a2.y += v2.y; a2.z += v2.z; a2.w += v2.w;
            a3.x += v3.x; a3.y += v3.y; a3.z += v3.z; a3.w += v3.w;
        }
    }
    float inv = 1.0f / (float)c;
    float4* vf = (float4*)(vox_feats + (size_t)t * 16);
    vf[0] = make_float4(a0.x * inv, a0.y * inv, a0.z * inv, a0.w * inv);
    vf[1] = make_float4(a1.x * inv, a1.y * inv, a1.z * inv, a1.w * inv);
    vf[2] = make_float4(a2.x * inv, a2.y * inv, a2.z * inv, a2.w * inv);
    vf[3] = make_float4(a3.x * inv, a3.y * inv, a3.z * inv, a3.w * inv);
}

extern "C" void kernel_launch(void* const* d_in, const int* in_sizes, int n_in,
                              void* d_out, int out_size, void* d_ws, size_t ws_size,
                              hipStream_t stream) {
    const int* coords = (const int*)d_in[0];
    const float* feats = (const float*)d_in[1];
    int N = in_sizes[0] / 4;

    float* out = (float*)d_out;
    float* vox_feats = out;                      // N*16
    float* vox_coords = out + (size_t)N * 16;    // N*4
    float* v2p = vox_coords + (size_t)N * 4;     // N
    float* nvox = v2p + (size_t)N;               // 1

    // NOTE: keyrec and mcnt are contiguous -> zeroed with ONE memset.
    char* w = (char*)d_ws;
    u32* keyrec = (u32*)w;     w += (size_t)NKEYS * 4;         // 28.3 MB (memset)
    u32* mcnt = (u32*)w;       w += (size_t)MCAP * 4;          // 2 MB (memset)
    u32* pkey = (u32*)w;       w += (size_t)N * 4;             // 8 MB
    u32* midx = (u32*)w;       w += (size_t)MCAP * MPAD * 4;   // 33.5 MB
    u64* voxinfo = (u64*)w;    w += (size_t)N * 8;             // 16 MB
    Combo* combo = (Combo*)w;  w += (size_t)NW * sizeof(Combo);// 3.5 MB
    u32* wprefix = (u32*)w;    w += (size_t)NW * 4;
    u32* mprefix = (u32*)w;    w += (size_t)NW * 4;
    u32* dtotal = (u32*)w;     w += 512 * 4;
    u32* mtotal = (u32*)w;     w += 512 * 4;
    u32* gidbase = (u32*)w;    w += 512 * 4;
    u32* mgidbase = (u32*)w;   w += 512 * 4;
    u32* rank48_d = (u32*)w;   w += (size_t)NTRIP * 4;
    u32* invrank_d = (u32*)w;  w += (size_t)NTRIP * 4;
    u32* nvslot = (u32*)w;     w += 256;

    hipMemcpyAsync(rank48_d, g_rank48, sizeof(g_rank48), hipMemcpyHostToDevice, stream);
    hipMemsetAsync(keyrec, 0, (size_t)NKEYS * 4 + (size_t)MCAP * 4, stream);

    int blocksN = (N + 255) / 256;

    k_key<<<blocksN, 256, 0, stream>>>(coords, rank48_d, pkey, keyrec, N);
    k_prefix<<<NBKT, 256, 0, stream>>>(keyrec, rank48_d, wprefix, mprefix,
                                       dtotal, mtotal, invrank_d);
    k_meta<<<1, 256, 0, stream>>>(dtotal, mtotal, gidbase, mgidbase, nvslot);
    k_emit<<<NBKT, 256, 0, stream>>>(keyrec, wprefix, mprefix, gidbase, mgidbase,
                                     invrank_d, combo, voxinfo);
    k_points<<<blocksN, 256, 0, stream>>>(pkey, combo, mcnt, midx, v2p, N);
    k_vox<<<blocksN, 256, 0, stream>>>(voxinfo, midx, feats, nvslot,
                                       vox_feats, vox_coords, nvox, N);
}

// Round 23
// 339.211 us; speedup vs baseline: 1.0951x; 1.0940x over previous
//
#include <hip/hip_runtime.h>
#include <vector>
#include <algorithm>
#include <utility>

typedef unsigned long long u64;
typedef unsigned int u32;

#define NTRIP 110592              // 48^3 distinct (c0,c1,c2)
#define NKEYS (NTRIP * 64)        // 7,077,888 possible keys (key <-> voxel bijection)
#define NW NTRIP                  // bitmap words
#define NBKT (NW / 256)           // 432 buckets of 256 words
#define MPAD 16                   // padded member slots per multi voxel (= one 64B line)
#define MCAP 524288               // max multi voxels supported (actual ~235K)

struct Combo {                    // 32B: what k_points needs per word
    u64 bm;                       // occupancy bits
    u64 mm;                       // multi bits
    u32 g;                        // gid base for this word
    u32 mg;                       // mgid base
    u32 iv;                       // (unused by k_points; kept for alignment)
    u32 pad;
};

// ======== host-side: rank table for the 110,592 triple-hashes ========
// full hash = fnv3p(c0,c1,c2) ^ c3 (c3 < 64 flips only low 6 bits).
// rank48[tau] = (rank_of_hash << 6) | (hash & 63); point key = rank48[tau]^c3 (23 bits)
static u32 g_rank48[NTRIP];
namespace {
struct RankInit {
    RankInit() {
        std::vector<std::pair<u64, u32>> v(NTRIP);
        for (u32 t = 0; t < NTRIP; t++) {
            u64 h = 14695981039346656037ull;
            const u64 P = 1099511628211ull;
            h *= P; h ^= (u64)(t / 2304);
            h *= P; h ^= (u64)((t % 2304) / 48);
            h *= P; h ^= (u64)(t % 48);
            h *= P;
            v[t] = {h, t};
        }
        std::sort(v.begin(), v.end());
        for (u32 p = 0; p < NTRIP; p++)
            g_rank48[v[p].second] = (p << 6) | (u32)(v[p].first & 63ull);
    }
};
static RankInit g_rank_init;
}

// ======== K1: key + ONE fire-and-forget atomic; keyrec[kk] = (idxsum<<8)|count ====
__global__ void k_key(const int* __restrict__ coords, const u32* __restrict__ rank48,
                      u32* __restrict__ pkey, u32* __restrict__ keyrec, int N) {
    int i = blockIdx.x * blockDim.x + threadIdx.x;
    if (i >= N) return;
    int4 c = ((const int4*)coords)[i];
    u32 tau = (u32)c.x * 2304u + (u32)c.y * 48u + (u32)c.z;
    u32 kk = rank48[tau] ^ (u32)c.w;
    atomicAdd(&keyrec[kk], ((u32)i << 8) | 1u);   // non-returning form
    pkey[i] = kk;
}

// ======== K2: popcount prefixes (bm/mm in registers) + invrank ========
__global__ void k_prefix(const u32* __restrict__ keyrec, const u32* __restrict__ rank48,
                         u32* __restrict__ wprefix, u32* __restrict__ mprefix,
                         u32* __restrict__ dtotal, u32* __restrict__ mtotal,
                         u32* __restrict__ invrank) {
    __shared__ u32 s[256];
    int t = threadIdx.x, b = blockIdx.x;
    int w = b * 256 + t;
    u32 r = rank48[w];
    invrank[r >> 6] = ((u32)w << 6) | (r & 63u);
    u64 bm = 0, mm = 0;
    const uint4* kr = (const uint4*)(keyrec + (size_t)w * 64);
#pragma unroll
    for (int q = 0; q < 16; q++) {
        uint4 v = kr[q];
        int bit = q * 4;
        u32 c0 = v.x & 0xFFu, c1 = v.y & 0xFFu, c2 = v.z & 0xFFu, c3v = v.w & 0xFFu;
        bm |= ((u64)(c0 ? 1u : 0u) << bit) | ((u64)(c1 ? 1u : 0u) << (bit + 1)) |
              ((u64)(c2 ? 1u : 0u) << (bit + 2)) | ((u64)(c3v ? 1u : 0u) << (bit + 3));
        mm |= ((u64)(c0 >= 2u ? 1u : 0u) << bit) | ((u64)(c1 >= 2u ? 1u : 0u) << (bit + 1)) |
              ((u64)(c2 >= 2u ? 1u : 0u) << (bit + 2)) | ((u64)(c3v >= 2u ? 1u : 0u) << (bit + 3));
    }
    u32 c = (u32)__popcll(bm);
    s[t] = c;
    __syncthreads();
    for (int off = 1; off < 256; off <<= 1) {
        u32 v = (t >= off) ? s[t - off] : 0u;
        __syncthreads();
        s[t] += v;
        __syncthreads();
    }
    wprefix[w] = s[t] - c;
    if (t == 255) dtotal[b] = s[255];
    __syncthreads();
    u32 m = (u32)__popcll(mm);
    s[t] = m;
    __syncthreads();
    for (int off = 1; off < 256; off <<= 1) {
        u32 v = (t >= off) ? s[t - off] : 0u;
        __syncthreads();
        s[t] += v;
        __syncthreads();
    }
    mprefix[w] = s[t] - m;
    if (t == 255) mtotal[b] = s[255];
}

// ======== K3: exclusive scans over the 432 buckets ========
__global__ void k_meta(const u32* __restrict__ dtotal, const u32* __restrict__ mtotal,
                       u32* __restrict__ gidbase, u32* __restrict__ mgidbase,
                       u32* __restrict__ nvslot) {
    __shared__ u32 s[256];
    int t = threadIdx.x;
    u32 a = (2 * t < NBKT) ? dtotal[2 * t] : 0u;
    u32 b = (2 * t + 1 < NBKT) ? dtotal[2 * t + 1] : 0u;
    u32 sum = a + b;
    s[t] = sum;
    __syncthreads();
    for (int off = 1; off < 256; off <<= 1) {
        u32 v = (t >= off) ? s[t - off] : 0u;
        __syncthreads();
        s[t] += v;
        __syncthreads();
    }
    u32 tb = s[t] - sum;
    if (2 * t < NBKT) gidbase[2 * t] = tb;
    if (2 * t + 1 < NBKT) gidbase[2 * t + 1] = tb + a;
    if (t == 255) nvslot[0] = s[255];
    __syncthreads();
    u32 a2 = (2 * t < NBKT) ? mtotal[2 * t] : 0u;
    u32 b2 = (2 * t + 1 < NBKT) ? mtotal[2 * t + 1] : 0u;
    u32 sum2 = a2 + b2;
    s[t] = sum2;
    __syncthreads();
    for (int off = 1; off < 256; off <<= 1) {
        u32 v = (t >= off) ? s[t - off] : 0u;
        __syncthreads();
        s[t] += v;
        __syncthreads();
    }
    u32 tb2 = s[t] - sum2;
    if (2 * t < NBKT) mgidbase[2 * t] = tb2;
    if (2 * t + 1 < NBKT) mgidbase[2 * t + 1] = tb2 + a2;
}

// ======== K3b: emit combo (for k_points) + voxinfo (for k_vox) ========
// voxinfo[gid] = pay(24) | c(8)<<24 | j(6)<<32 | iv(23)<<38
__global__ void k_emit(const u32* __restrict__ keyrec, const u32* __restrict__ wprefix,
                       const u32* __restrict__ mprefix, const u32* __restrict__ gidbase,
                       const u32* __restrict__ mgidbase, const u32* __restrict__ invrank,
                       Combo* __restrict__ combo, u64* __restrict__ voxinfo) {
    int w = blockIdx.x * 256 + threadIdx.x;
    u32 g = gidbase[w >> 8] + wprefix[w];
    u32 mg = mgidbase[w >> 8] + mprefix[w];
    u32 iv = invrank[w];
    u64 bm = 0, mm = 0;
    u32 gg = g, mgg = mg;
    const u32* kr = keyrec + (size_t)w * 64;
#pragma unroll 4
    for (int j = 0; j < 64; j++) {
        u32 rec = kr[j];
        u32 c = rec & 0xFFu;
        if (c) {
            bm |= 1ull << j;
            u32 pay;
            if (c >= 2u) {
                mm |= 1ull << j;
                pay = mgg++;
            } else {
                pay = (rec >> 8) & 0xFFFFFFu;
            }
            u32 cc = c > MPAD ? (u32)MPAD : c;
            voxinfo[gg++] = (u64)pay | ((u64)cc << 24) | ((u64)(u32)j << 32) |
                            ((u64)iv << 38);
        }
    }
    Combo cb;
    cb.bm = bm; cb.mm = mm; cb.g = g; cb.mg = mg; cb.iv = iv; cb.pad = 0;
    combo[w] = cb;
}

// ======== K4: per point -- v2p + midx (multis only) ========
__global__ void k_points(const u32* __restrict__ pkey, const Combo* __restrict__ combo,
                         u32* __restrict__ mcnt, u32* __restrict__ midx,
                         float* __restrict__ v2p, int N) {
    int i = blockIdx.x * blockDim.x + threadIdx.x;
    if (i >= N) return;
    u32 kk = pkey[i];
    Combo cb = combo[kk >> 6];                 // ONE 32B gather
    u64 lowmask = (1ull << (kk & 63u)) - 1ull;
    u32 gid = cb.g + (u32)__popcll(cb.bm & lowmask);
    v2p[i] = (float)gid;                       // coalesced
    if ((cb.mm >> (kk & 63u)) & 1ull) {
        u32 mgid = cb.mg + (u32)__popcll(cb.mm & lowmask);
        u32 slot = atomicAdd(&mcnt[mgid], 1u);
        if (slot < MPAD) midx[(size_t)mgid * MPAD + slot] = (u32)i;
    }
    // singletons: index already in voxinfo payload (keyrec idxsum)
}

// ======== K5: thread-per-output-row; coalesced meta, gathered feats ========
__global__ void k_vox(const u64* __restrict__ voxinfo, const u32* __restrict__ midx,
                      const float* __restrict__ feats, const u32* __restrict__ nvslot,
                      float* __restrict__ vox_feats, float* __restrict__ vox_coords,
                      float* __restrict__ nvox, int N) {
    int t = blockIdx.x * blockDim.x + threadIdx.x;
    if (t >= N) return;
    u32 nv = nvslot[0];
    if (t == 0) nvox[0] = (float)nv;
    if ((u32)t >= nv) {   // padding rows
        float4 z = {0, 0, 0, 0};
        float4* vf = (float4*)(vox_feats + (size_t)t * 16);
        vf[0] = z; vf[1] = z; vf[2] = z; vf[3] = z;
        *(float4*)(vox_coords + (size_t)t * 4) = z;
        return;
    }
    u64 vi = voxinfo[t];                            // coalesced 8B
    u32 pay = (u32)vi & 0xFFFFFFu;
    u32 c = (u32)(vi >> 24) & 0xFFu;
    u32 j = (u32)(vi >> 32) & 63u;
    u32 iv = (u32)(vi >> 38);
    u32 tau = iv >> 6;
    u32 c3 = (j ^ iv) & 63u;
    *(float4*)(vox_coords + (size_t)t * 4) =
        make_float4((float)(tau / 2304u), (float)((tau % 2304u) / 48u),
                    (float)(tau % 48u), (float)c3);
    u32 ii[MPAD];
    ii[0] = pay;                    // singleton: pay == point index
#pragma unroll
    for (int q = 1; q < MPAD; q++) ii[q] = 0u;
    if (c > 1) {
        const uint4* ml = (const uint4*)(midx + (size_t)pay * MPAD);
        uint4 L0 = ml[0], L1 = ml[1], L2 = ml[2], L3 = ml[3];
        ii[0] = L0.x; ii[1] = L0.y; ii[2] = L0.z; ii[3] = L0.w;
        ii[4] = L1.x; ii[5] = L1.y; ii[6] = L1.z; ii[7] = L1.w;
        ii[8] = L2.x; ii[9] = L2.y; ii[10] = L2.z; ii[11] = L2.w;
        ii[12] = L3.x; ii[13] = L3.y; ii[14] = L3.z; ii[15] = L3.w;
    }
    float4 a0 = {0, 0, 0, 0}, a1 = {0, 0, 0, 0}, a2 = {0, 0, 0, 0}, a3 = {0, 0, 0, 0};
#pragma unroll
    for (int q = 0; q < MPAD; q++) {
        if (q < (int)c) {
            const float4* f = (const float4*)(feats + (size_t)ii[q] * 16);
            float4 v0 = f[0], v1 = f[1], v2 = f[2], v3 = f[3];
            a0.x += v0.x; a0.y += v0.y; a0.z += v0.z; a0.w += v0.w;
            a1.x += v1.x; a1.y += v1.y; a1.z += v1.z; a1.w += v1.w;
            a2.x += v2.x; a2.y += v2.y; a2.z += v2.z; a2.w += v2.w;
            a3.x += v3.x; a3.y += v3.y; a3.z += v3.z; a3.w += v3.w;
        }
    }
    float inv = 1.0f / (float)c;
    float4* vf = (float4*)(vox_feats + (size_t)t * 16);
    vf[0] = make_float4(a0.x * inv, a0.y * inv, a0.z * inv, a0.w * inv);
    vf[1] = make_float4(a1.x * inv, a1.y * inv, a1.z * inv, a1.w * inv);
    vf[2] = make_float4(a2.x * inv, a2.y * inv, a2.z * inv, a2.w * inv);
    vf[3] = make_float4(a3.x * inv, a3.y * inv, a3.z * inv, a3.w * inv);
}

extern "C" void kernel_launch(void* const* d_in, const int* in_sizes, int n_in,
                              void* d_out, int out_size, void* d_ws, size_t ws_size,
                              hipStream_t stream) {
    const int* coords = (const int*)d_in[0];
    const float* feats = (const float*)d_in[1];
    int N = in_sizes[0] / 4;

    float* out = (float*)d_out;
    float* vox_feats = out;                      // N*16
    float* vox_coords = out + (size_t)N * 16;    // N*4
    float* v2p = vox_coords + (size_t)N * 4;     // N
    float* nvox = v2p + (size_t)N;               // 1

    // NOTE: keyrec and mcnt are contiguous -> zeroed with ONE memset.
    char* w = (char*)d_ws;
    u32* keyrec = (u32*)w;     w += (size_t)NKEYS * 4;         // 28.3 MB (memset)
    u32* mcnt = (u32*)w;       w += (size_t)MCAP * 4;          // 2 MB (memset)
    u32* pkey = (u32*)w;       w += (size_t)N * 4;             // 8 MB
    u32* midx = (u32*)w;       w += (size_t)MCAP * MPAD * 4;   // 33.5 MB
    u64* voxinfo = (u64*)w;    w += (size_t)N * 8;             // 16 MB
    Combo* combo = (Combo*)w;  w += (size_t)NW * sizeof(Combo);// 3.5 MB
    u32* wprefix = (u32*)w;    w += (size_t)NW * 4;
    u32* mprefix = (u32*)w;    w += (size_t)NW * 4;
    u32* dtotal = (u32*)w;     w += 512 * 4;
    u32* mtotal = (u32*)w;     w += 512 * 4;
    u32* gidbase = (u32*)w;    w += 512 * 4;
    u32* mgidbase = (u32*)w;   w += 512 * 4;
    u32* rank48_d = (u32*)w;   w += (size_t)NTRIP * 4;
    u32* invrank_d = (u32*)w;  w += (size_t)NTRIP * 4;
    u32* nvslot = (u32*)w;     w += 256;

    hipMemcpyAsync(rank48_d, g_rank48, sizeof(g_rank48), hipMemcpyHostToDevice, stream);
    hipMemsetAsync(keyrec, 0, (size_t)NKEYS * 4 + (size_t)MCAP * 4, stream);

    int blocksN = (N + 255) / 256;

    k_key<<<blocksN, 256, 0, stream>>>(coords, rank48_d, pkey, keyrec, N);
    k_prefix<<<NBKT, 256, 0, stream>>>(keyrec, rank48_d, wprefix, mprefix,
                                       dtotal, mtotal, invrank_d);
    k_meta<<<1, 256, 0, stream>>>(dtotal, mtotal, gidbase, mgidbase, nvslot);
    k_emit<<<NBKT, 256, 0, stream>>>(keyrec, wprefix, mprefix, gidbase, mgidbase,
                                     invrank_d, combo, voxinfo);
    k_points<<<blocksN, 256, 0, stream>>>(pkey, combo, mcnt, midx, v2p, N);
    k_vox<<<blocksN, 256, 0, stream>>>(voxinfo, midx, feats, nvslot,
                                       vox_feats, vox_coords, nvox, N);
}